// Round 5
// baseline (123.035 us; speedup 1.0000x reference)
//
#include <hip/hip_runtime.h>
#include <math.h>

// Problem geometry (fixed by setup_inputs)
#define NT    32
#define NA    64
#define NB    64
#define NGEO  128
#define NELEM (NT * NA * NB * NGEO)   // 16777216 = 2^24
#define GR    64
#define NQ    (GR * GR * GR)          // 262144 quad cells
#define QBYTES ((size_t)NQ * 16)      // 4 MiB

#define THREADS 256
#define BLOCKS  4096
#define NTHREAD (BLOCKS * THREADS)     // 2^20 threads
#define NITER   (NELEM / 4 / NTHREAD)  // 4 chunks per thread

// clang ext-vector float4 (HIP_vector_type float4 is rejected by the
// nontemporal builtins). Same layout, same dwordx4 codegen.
typedef float vf4 __attribute__((ext_vector_type(4)));

// ---------------------------------------------------------------------------
// Pre-pass: pack each voxel's (y,z) 2x2 face into one aligned float4 so the
// main kernel's 8 divergent 4B gathers become 2 divergent 16B gathers.
// Q[x][y][z] = { g(x,y,z), g(x,y,z+1), g(x,y+1,z), g(x,y+1,z+1) }
__global__ __launch_bounds__(256) void build_quads(
    const float* __restrict__ g, vf4* __restrict__ q)
{
    int idx = blockIdx.x * 256 + threadIdx.x;          // 0 .. NQ-1
    int z = idx & 63, y = (idx >> 6) & 63, x = idx >> 12;
    int zc = min(z + 1, 63), yc = min(y + 1, 63);
    const float* gx = g + x * 4096;
    vf4 v;
    v.x = gx[y  * 64 + z];  v.y = gx[y  * 64 + zc];
    v.z = gx[yc * 64 + z];  v.w = gx[yc * 64 + zc];
    q[idx] = v;
}

// ---------------------------------------------------------------------------
// Phase A result for one point: mask, cell index, interp weights.
// Accuracy contract (absmax threshold = 2% of max output):
//  * MASK decisions (t_rot>=0, 2<=r<=10, |z|<=4) bit-match the numpy f32
//    reference -> __f*_rn intrinsics (no fp-contract) + rounded sqrtf.
//    Verified absmax==0.0 in R1/R2/R4.
//  * Value path (rotation, weights, sigmoid) is continuous; hardware
//    v_sin/v_cos/v_exp/v_rcp give ~1e-5 relative error, ~1000x under
//    threshold.
struct Prep {
    int   bidx;
    bool  alive;
    float wx0, wx1, wy0, wy1, wz0, wz1;
};

__device__ __forceinline__ Prep prep_point(
    float x, float y, float z, float Om, float tg, float tM, float tinj)
{
    Prep p;
    float t_rot = __fsub_rn(__fsub_rn(tM, tg), tinj);
    float r2 = __fadd_rn(__fadd_rn(__fmul_rn(x, x), __fmul_rn(y, y)),
                         __fmul_rn(z, z));
    float r = sqrtf(r2);

    p.alive = (t_rot >= 0.0f) & (r >= 2.0f) & (r <= 10.0f) &
              (fabsf(z) <= 4.0f);

    // warp-back rotation about z (hardware sin/cos take revolutions)
    float theta = -Om * t_rot;
    float rev = theta * 0.15915494309189535f;
    rev = rev - floorf(rev);
    float s = __builtin_amdgcn_sinf(rev);
    float c = __builtin_amdgcn_cosf(rev);
    float xw = x * c - y * s;
    float yw = x * s + y * c;

    // grid index space: (v + 10) / 20 * 63, clamped into [0, 63)
    float fx = (xw + 10.0f) * 3.15f;
    float fy = (yw + 10.0f) * 3.15f;
    float fz = (z  + 10.0f) * 3.15f;
    fx = fminf(fmaxf(fx, 0.0f), 62.999996f);
    fy = fminf(fmaxf(fy, 0.0f), 62.999996f);
    fz = fminf(fmaxf(fz, 0.0f), 62.999996f);

    int ix0 = (int)fx, iy0 = (int)fy, iz0 = (int)fz;
    p.wx1 = fx - (float)ix0; p.wy1 = fy - (float)iy0; p.wz1 = fz - (float)iz0;
    p.wx0 = 1.0f - p.wx1;    p.wy0 = 1.0f - p.wy1;    p.wz0 = 1.0f - p.wz1;

    int bidx = ix0 * 4096 + iy0 * 64 + iz0;
    p.bidx = p.alive ? bidx : 0;   // dead lanes: broadcast line, no branch
    return p;
}

__device__ __forceinline__ float finish_point(
    const Prep& p, vf4 q0, vf4 q1)
{
    float c00 = q0.x * p.wz0 + q0.y * p.wz1;
    float c01 = q0.z * p.wz0 + q0.w * p.wz1;
    float c10 = q1.x * p.wz0 + q1.y * p.wz1;
    float c11 = q1.z * p.wz0 + q1.w * p.wz1;
    float c0  = c00 * p.wy0 + c01 * p.wy1;
    float c1  = c10 * p.wy0 + c11 * p.wy1;
    float net = c0 * p.wx0 + c1 * p.wx1;

    float E = __expf(10.0f - net);                 // sigmoid(net - 10)
    float sig = __builtin_amdgcn_rcpf(1.0f + E);
    return p.alive ? sig : 0.0f;
}

#define NTLOAD(ptr)  __builtin_nontemporal_load((const vf4*)(ptr))

template <bool QUAD>
__global__ __launch_bounds__(256) void grid_predictor_kernel(
    const float* __restrict__ t_frames,
    const float* __restrict__ coords,
    const float* __restrict__ Omega,
    const float* __restrict__ t_geos,
    const float* __restrict__ t_inj,
    const float* __restrict__ t_start,
    const void*  __restrict__ tbl,     // quad table (QUAD) or raw grid
    float* __restrict__ out)
{
    int tid = blockIdx.x * THREADS + threadIdx.x;
    float tinj = t_inj[0];
    float ts0  = t_start[0];

    int i = tid * 4;
    // prologue: stream chunk 0
    vf4 x4 = NTLOAD(coords + i);
    vf4 y4 = NTLOAD(coords + NELEM + i);
    vf4 z4 = NTLOAD(coords + 2 * NELEM + i);
    vf4 o4 = NTLOAD(Omega + i);
    vf4 g4 = NTLOAD(t_geos + i);

    #pragma unroll
    for (int j = 0; j < NITER; ++j) {
        int inext = i + NTHREAD * 4;
        // prefetch next chunk's streams: issue BEFORE current compute so
        // HBM latency runs under this iteration's mask/gather/interp work.
        vf4 nx, ny, nz, no, ng;
        if (j + 1 < NITER) {
            nx = NTLOAD(coords + inext);
            ny = NTLOAD(coords + NELEM + inext);
            nz = NTLOAD(coords + 2 * NELEM + inext);
            no = NTLOAD(Omega + inext);
            ng = NTLOAD(t_geos + inext);
        }

        int t = i >> 19;                       // uniform per wave
        float tM = __fsub_rn(t_frames[t], ts0);

        // phase A: masks + cell addresses + weights for all 4 points
        Prep p0 = prep_point(x4.x, y4.x, z4.x, o4.x, g4.x, tM, tinj);
        Prep p1 = prep_point(x4.y, y4.y, z4.y, o4.y, g4.y, tM, tinj);
        Prep p2 = prep_point(x4.z, y4.z, z4.z, o4.z, g4.z, tM, tinj);
        Prep p3 = prep_point(x4.w, y4.w, z4.w, o4.w, g4.w, tM, tinj);

        // phase B: all 8 gathers in flight together
        vf4 a0, b0, a1, b1, a2, b2, a3, b3;
        if (QUAD) {
            const vf4* q = (const vf4*)tbl;
            a0 = q[p0.bidx]; b0 = q[p0.bidx + 4096];
            a1 = q[p1.bidx]; b1 = q[p1.bidx + 4096];
            a2 = q[p2.bidx]; b2 = q[p2.bidx + 4096];
            a3 = q[p3.bidx]; b3 = q[p3.bidx + 4096];
        } else {
            const float* g = (const float*)tbl;
            const float* h;
            h = g + p0.bidx; a0 = (vf4){h[0], h[1], h[64], h[65]};
                             b0 = (vf4){h[4096], h[4097], h[4160], h[4161]};
            h = g + p1.bidx; a1 = (vf4){h[0], h[1], h[64], h[65]};
                             b1 = (vf4){h[4096], h[4097], h[4160], h[4161]};
            h = g + p2.bidx; a2 = (vf4){h[0], h[1], h[64], h[65]};
                             b2 = (vf4){h[4096], h[4097], h[4160], h[4161]};
            h = g + p3.bidx; a3 = (vf4){h[0], h[1], h[64], h[65]};
                             b3 = (vf4){h[4096], h[4097], h[4160], h[4161]};
        }

        // phase C: interpolate + sigmoid + mask
        vf4 r;
        r.x = finish_point(p0, a0, b0);
        r.y = finish_point(p1, a1, b1);
        r.z = finish_point(p2, a2, b2);
        r.w = finish_point(p3, a3, b3);
        __builtin_nontemporal_store(r, (vf4*)(out + i));

        x4 = nx; y4 = ny; z4 = nz; o4 = no; g4 = ng;
        i = inext;
    }
}

extern "C" void kernel_launch(void* const* d_in, const int* in_sizes, int n_in,
                              void* d_out, int out_size, void* d_ws, size_t ws_size,
                              hipStream_t stream) {
    const float* t_frames = (const float*)d_in[0];
    const float* coords   = (const float*)d_in[1];
    const float* Omega    = (const float*)d_in[2];
    const float* t_geos   = (const float*)d_in[3];
    const float* t_inj    = (const float*)d_in[4];
    const float* t_start  = (const float*)d_in[5];
    const float* grid     = (const float*)d_in[6];
    float* out = (float*)d_out;

    if (ws_size >= QBYTES) {
        vf4* q = (vf4*)d_ws;
        build_quads<<<NQ / 256, 256, 0, stream>>>(grid, q);
        grid_predictor_kernel<true><<<BLOCKS, THREADS, 0, stream>>>(
            t_frames, coords, Omega, t_geos, t_inj, t_start, q, out);
    } else {
        grid_predictor_kernel<false><<<BLOCKS, THREADS, 0, stream>>>(
            t_frames, coords, Omega, t_geos, t_inj, t_start, grid, out);
    }
}

// Round 6
// 91.380 us; speedup vs baseline: 1.3464x; 1.3464x over previous
//
#include <hip/hip_runtime.h>
#include <hip/hip_fp16.h>
#include <math.h>

// Problem geometry (fixed by setup_inputs)
#define NT    32
#define NA    64
#define NB    64
#define NGEO  128
#define NELEM (NT * NA * NB * NGEO)   // 16777216 = 2^24
#define GR    64
#define NQ    (GR * GR * GR)          // 262144 cells
#define QBYTES ((size_t)NQ * 16)      // 4 MiB packed fp16-cube table

// clang ext-vector types (HIP_vector_type is rejected by the nontemporal
// builtins). Same layout / codegen as float4 & uint4.
typedef float        vf4 __attribute__((ext_vector_type(4)));
typedef unsigned int vu4 __attribute__((ext_vector_type(4)));

// ---------------------------------------------------------------------------
// Pre-pass: pack each cell's full 2x2x2 corner cube as 8 x fp16 in ONE 16B
// record -> the main kernel does a single aligned dwordx4 gather per point
// (was 2 in R4, 8 in R2). fp16 value error <= 2^-11 relative (grid |v|~10
// -> net error <=0.005 -> <=0.5% emission error, 4x under the 2% threshold).
// rec = { v000,v001 | v010,v011 | v100,v101 | v110,v111 } packed lo/hi.
__global__ __launch_bounds__(256) void build_cube(
    const float* __restrict__ g, vu4* __restrict__ q)
{
    int idx = blockIdx.x * 256 + threadIdx.x;          // 0 .. NQ-1
    int z = idx & 63, y = (idx >> 6) & 63, x = idx >> 12;
    int zc = min(z + 1, 63), yc = min(y + 1, 63), xc = min(x + 1, 63);
    const float* g0 = g + x  * 4096;
    const float* g1 = g + xc * 4096;
    int b00 = y * 64 + z,  b01 = y * 64 + zc;
    int b10 = yc * 64 + z, b11 = yc * 64 + zc;

    auto pack2 = [](float a, float b) -> unsigned {
        unsigned lo = __half_as_ushort(__float2half(a));
        unsigned hi = __half_as_ushort(__float2half(b));
        return lo | (hi << 16);
    };
    vu4 v;
    v.x = pack2(g0[b00], g0[b01]);
    v.y = pack2(g0[b10], g0[b11]);
    v.z = pack2(g1[b00], g1[b01]);
    v.w = pack2(g1[b10], g1[b11]);
    q[idx] = v;
}

// ---------------------------------------------------------------------------
// Accuracy contract (absmax threshold = 2% of max output):
//  * MASK decisions (t_rot>=0, 2<=r<=10, |z|<=4) bit-match the numpy f32
//    reference -> __f*_rn intrinsics (no fp-contract) + rounded sqrtf.
//    Verified absmax==0.0 in R1/R2/R4/R5.
//  * Value path (rotation, weights, fp16 table, sigmoid) is continuous;
//    worst-case ~0.5% relative emission error, 4x under threshold.
struct Prep {
    int   bidx;
    bool  alive;
    float wx0, wx1, wy0, wy1, wz0, wz1;
};

__device__ __forceinline__ Prep prep_point(
    float x, float y, float z, float Om, float tg, float tM, float tinj)
{
    Prep p;
    float t_rot = __fsub_rn(__fsub_rn(tM, tg), tinj);
    float r2 = __fadd_rn(__fadd_rn(__fmul_rn(x, x), __fmul_rn(y, y)),
                         __fmul_rn(z, z));
    float r = sqrtf(r2);

    p.alive = (t_rot >= 0.0f) & (r >= 2.0f) & (r <= 10.0f) &
              (fabsf(z) <= 4.0f);

    // warp-back rotation about z (hardware sin/cos take revolutions)
    float theta = -Om * t_rot;
    float rev = theta * 0.15915494309189535f;
    rev = rev - floorf(rev);
    float s = __builtin_amdgcn_sinf(rev);
    float c = __builtin_amdgcn_cosf(rev);
    float xw = x * c - y * s;
    float yw = x * s + y * c;

    // grid index space: (v + 10) / 20 * 63, clamped into [0, 63)
    float fx = (xw + 10.0f) * 3.15f;
    float fy = (yw + 10.0f) * 3.15f;
    float fz = (z  + 10.0f) * 3.15f;
    fx = fminf(fmaxf(fx, 0.0f), 62.999996f);
    fy = fminf(fmaxf(fy, 0.0f), 62.999996f);
    fz = fminf(fmaxf(fz, 0.0f), 62.999996f);

    int ix0 = (int)fx, iy0 = (int)fy, iz0 = (int)fz;
    p.wx1 = fx - (float)ix0; p.wy1 = fy - (float)iy0; p.wz1 = fz - (float)iz0;
    p.wx0 = 1.0f - p.wx1;    p.wy0 = 1.0f - p.wy1;    p.wz0 = 1.0f - p.wz1;

    int bidx = ix0 * 4096 + iy0 * 64 + iz0;
    p.bidx = p.alive ? bidx : 0;   // dead lanes: broadcast line, no branch
    return p;
}

__device__ __forceinline__ float2 cvt2(unsigned u)
{
    __half2 h = *reinterpret_cast<__half2*>(&u);
    return __half22float2(h);      // 2x v_cvt_f32_f16
}

__device__ __forceinline__ float finish_point(const Prep& p, vu4 cbe)
{
    float2 q00 = cvt2(cbe.x);      // v000, v001
    float2 q01 = cvt2(cbe.y);      // v010, v011
    float2 q10 = cvt2(cbe.z);      // v100, v101
    float2 q11 = cvt2(cbe.w);      // v110, v111

    float c00 = q00.x * p.wz0 + q00.y * p.wz1;
    float c01 = q01.x * p.wz0 + q01.y * p.wz1;
    float c10 = q10.x * p.wz0 + q10.y * p.wz1;
    float c11 = q11.x * p.wz0 + q11.y * p.wz1;
    float c0  = c00 * p.wy0 + c01 * p.wy1;
    float c1  = c10 * p.wy0 + c11 * p.wy1;
    float net = c0 * p.wx0 + c1 * p.wx1;

    float E = __expf(10.0f - net);                 // sigmoid(net - 10)
    float sig = __builtin_amdgcn_rcpf(1.0f + E);
    return p.alive ? sig : 0.0f;
}

#define NTLOAD(ptr)  __builtin_nontemporal_load((const vf4*)(ptr))

// One-shot structure (R4's proven best): 4 points/thread, no loop.
template <bool CUBE>
__global__ __launch_bounds__(256) void grid_predictor_kernel(
    const float* __restrict__ t_frames,
    const float* __restrict__ coords,
    const float* __restrict__ Omega,
    const float* __restrict__ t_geos,
    const float* __restrict__ t_inj,
    const float* __restrict__ t_start,
    const void*  __restrict__ tbl,     // fp16-cube table (CUBE) or raw grid
    float* __restrict__ out)
{
    int i = (blockIdx.x * 256 + threadIdx.x) * 4;

    int t = blockIdx.x >> 9;                       // t uniform per block
    float tM   = __fsub_rn(t_frames[t], t_start[0]);
    float tinj = t_inj[0];

    // Non-temporal streams: zero reuse, keep them out of L2 so the 4MB
    // table stays resident.
    vf4 x4 = NTLOAD(coords + i);
    vf4 y4 = NTLOAD(coords + NELEM + i);
    vf4 z4 = NTLOAD(coords + 2 * NELEM + i);
    vf4 o4 = NTLOAD(Omega + i);
    vf4 g4 = NTLOAD(t_geos + i);

    // phase A: masks + cell addresses + weights for all 4 points
    Prep p0 = prep_point(x4.x, y4.x, z4.x, o4.x, g4.x, tM, tinj);
    Prep p1 = prep_point(x4.y, y4.y, z4.y, o4.y, g4.y, tM, tinj);
    Prep p2 = prep_point(x4.z, y4.z, z4.z, o4.z, g4.z, tM, tinj);
    Prep p3 = prep_point(x4.w, y4.w, z4.w, o4.w, g4.w, tM, tinj);

    vf4 r;
    if (CUBE) {
        // phase B: ONE 16B gather per point, all 4 in flight together
        const vu4* q = (const vu4*)tbl;
        vu4 c0 = q[p0.bidx];
        vu4 c1 = q[p1.bidx];
        vu4 c2 = q[p2.bidx];
        vu4 c3 = q[p3.bidx];
        // phase C: unpack + interpolate + sigmoid + mask
        r.x = finish_point(p0, c0);
        r.y = finish_point(p1, c1);
        r.z = finish_point(p2, c2);
        r.w = finish_point(p3, c3);
    } else {
        // fallback: raw f32 grid, 8 scalar gathers per point
        const float* g = (const float*)tbl;
        #pragma unroll
        for (int k = 0; k < 4; ++k) {
            const Prep& p = k == 0 ? p0 : k == 1 ? p1 : k == 2 ? p2 : p3;
            const float* h = g + p.bidx;
            float c00 = h[0]    * p.wz0 + h[1]    * p.wz1;
            float c01 = h[64]   * p.wz0 + h[65]   * p.wz1;
            float c10 = h[4096] * p.wz0 + h[4097] * p.wz1;
            float c11 = h[4160] * p.wz0 + h[4161] * p.wz1;
            float c0  = c00 * p.wy0 + c01 * p.wy1;
            float c1  = c10 * p.wy0 + c11 * p.wy1;
            float net = c0 * p.wx0 + c1 * p.wx1;
            float E = __expf(10.0f - net);
            float v = __builtin_amdgcn_rcpf(1.0f + E);
            v = p.alive ? v : 0.0f;
            if (k == 0) r.x = v; else if (k == 1) r.y = v;
            else if (k == 2) r.z = v; else r.w = v;
        }
    }

    __builtin_nontemporal_store(r, (vf4*)(out + i));
}

extern "C" void kernel_launch(void* const* d_in, const int* in_sizes, int n_in,
                              void* d_out, int out_size, void* d_ws, size_t ws_size,
                              hipStream_t stream) {
    const float* t_frames = (const float*)d_in[0];
    const float* coords   = (const float*)d_in[1];
    const float* Omega    = (const float*)d_in[2];
    const float* t_geos   = (const float*)d_in[3];
    const float* t_inj    = (const float*)d_in[4];
    const float* t_start  = (const float*)d_in[5];
    const float* grid     = (const float*)d_in[6];
    float* out = (float*)d_out;

    const int threads = 256;
    const int blocks = NELEM / 4 / threads;        // 16384

    if (ws_size >= QBYTES) {
        vu4* q = (vu4*)d_ws;
        build_cube<<<NQ / 256, 256, 0, stream>>>(grid, q);
        grid_predictor_kernel<true><<<blocks, threads, 0, stream>>>(
            t_frames, coords, Omega, t_geos, t_inj, t_start, q, out);
    } else {
        grid_predictor_kernel<false><<<blocks, threads, 0, stream>>>(
            t_frames, coords, Omega, t_geos, t_inj, t_start, grid, out);
    }
}